// Round 1
// baseline (2740.926 us; speedup 1.0000x reference)
//
#include <hip/hip_runtime.h>
#include <math.h>

#define NN 100000
#define NE 1600000
#define IN_DIM 512
#define HID 128
#define N_LAYERS 8

// ---------------- CSR build ----------------

__global__ void deg_count_kernel(const int* __restrict__ dst, int* __restrict__ deg) {
    int e = blockIdx.x * blockDim.x + threadIdx.x;
    if (e < NE) atomicAdd(&deg[dst[e]], 1);
}

__global__ void dinv_kernel(const int* __restrict__ deg, float* __restrict__ dinv) {
    int i = blockIdx.x * blockDim.x + threadIdx.x;
    if (i < NN) dinv[i] = rsqrtf((float)(deg[i] + 1));   // +1 self loop
}

// single-block exclusive scan of deg -> row_ptr (and cursor copy)
__global__ void scan_kernel(const int* __restrict__ deg, int* __restrict__ row_ptr,
                            int* __restrict__ cursor) {
    __shared__ int sm[1024];
    __shared__ int run;
    int tid = threadIdx.x;
    if (tid == 0) run = 0;
    __syncthreads();
    for (int base = 0; base < NN; base += 1024) {
        int i = base + tid;
        int v = (i < NN) ? deg[i] : 0;
        sm[tid] = v;
        __syncthreads();
        for (int off = 1; off < 1024; off <<= 1) {
            int t = (tid >= off) ? sm[tid - off] : 0;
            __syncthreads();
            sm[tid] += t;
            __syncthreads();
        }
        if (i < NN) {
            int o = run + sm[tid] - v;   // exclusive
            row_ptr[i] = o;
            cursor[i] = o;
        }
        __syncthreads();
        if (tid == 0) run += sm[1023];
        __syncthreads();
    }
    if (tid == 0) row_ptr[NN] = run;
}

__global__ void fill_kernel(const int* __restrict__ src, const int* __restrict__ dst,
                            const float* __restrict__ dinv, int* __restrict__ cursor,
                            int* __restrict__ col, float* __restrict__ val) {
    int e = blockIdx.x * blockDim.x + threadIdx.x;
    if (e < NE) {
        int s = src[e], d = dst[e];
        int pos = atomicAdd(&cursor[d], 1);
        col[pos] = s;
        val[pos] = dinv[s] * dinv[d];
    }
}

// ---------------- initial projection: x[NN][512] @ W[512][128] + b ----------------

__global__ __launch_bounds__(256) void init_gemm_kernel(
    const float* __restrict__ x, const float* __restrict__ W,
    const float* __restrict__ b, float* __restrict__ out, float* __restrict__ x0) {
    __shared__ float xs[32][132];           // +4 pad keeps float4 alignment, no conflicts
    int col = threadIdx.x & 127;
    int rh  = threadIdx.x >> 7;             // 0/1
    int row0 = blockIdx.x * 32;

    float acc[16];
#pragma unroll
    for (int r = 0; r < 16; ++r) acc[r] = 0.f;

    for (int kc = 0; kc < IN_DIM; kc += 128) {
        __syncthreads();
        for (int t = threadIdx.x; t < 32 * 128; t += 256) {
            int r = t >> 7, k = t & 127;
            xs[r][k] = x[(size_t)(row0 + r) * IN_DIM + kc + k];
        }
        __syncthreads();
        for (int k = 0; k < 128; k += 4) {
            float4 wv;
            wv.x = W[(size_t)(kc + k + 0) * HID + col];
            wv.y = W[(size_t)(kc + k + 1) * HID + col];
            wv.z = W[(size_t)(kc + k + 2) * HID + col];
            wv.w = W[(size_t)(kc + k + 3) * HID + col];
#pragma unroll
            for (int r = 0; r < 16; ++r) {
                float4 hv = *(const float4*)&xs[rh * 16 + r][k];
                acc[r] += hv.x * wv.x + hv.y * wv.y + hv.z * wv.z + hv.w * wv.w;
            }
        }
    }
    float bias = b[col];
#pragma unroll
    for (int r = 0; r < 16; ++r) {
        float v = acc[r] + bias;
        size_t o = (size_t)(row0 + rh * 16 + r) * HID + col;
        out[o] = v;
        x0[o]  = v;
    }
}

// ---------------- sparse aggregation: one wave per node ----------------

__global__ __launch_bounds__(256) void agg_kernel(
    const float* __restrict__ x, const float* __restrict__ x0,
    const int* __restrict__ row_ptr, const int* __restrict__ col,
    const float* __restrict__ val, const float* __restrict__ dinv,
    float* __restrict__ H) {
    int node = blockIdx.x * 4 + (threadIdx.x >> 6);
    int lane = threadIdx.x & 63;

    float di = dinv[node];
    const float2* xr = (const float2*)(x + (size_t)node * HID);
    float2 a = xr[lane];
    float2 acc;
    acc.x = di * di * a.x;                  // self loop
    acc.y = di * di * a.y;

    int p  = row_ptr[node];
    int pe = row_ptr[node + 1];
    for (; p < pe; ++p) {
        int   s = col[p];
        float w = val[p];
        const float2* sr = (const float2*)(x + (size_t)s * HID);
        float2 bv = sr[lane];
        acc.x += w * bv.x;
        acc.y += w * bv.y;
    }
    const float2* zr = (const float2*)(x0 + (size_t)node * HID);
    float2 z = zr[lane];
    float2 h;
    h.x = 0.9f * acc.x + 0.1f * z.x;
    h.y = 0.9f * acc.y + 0.1f * z.y;
    ((float2*)(H + (size_t)node * HID))[lane] = h;
}

// ---------------- fused layer GEMM: x = relu((1-b)h + b*(h@W)), in place ----------------

__global__ __launch_bounds__(256) void layer_gemm_kernel(
    float* __restrict__ H, const float* __restrict__ W, float beta) {
    __shared__ float hs[32][132];
    int col = threadIdx.x & 127;
    int rh  = threadIdx.x >> 7;
    int row0 = blockIdx.x * 32;

    for (int t = threadIdx.x; t < 32 * 128; t += 256) {
        int r = t >> 7, k = t & 127;
        hs[r][k] = H[(size_t)(row0 + r) * HID + k];
    }
    __syncthreads();

    float acc[16];
#pragma unroll
    for (int r = 0; r < 16; ++r) acc[r] = 0.f;

    for (int k = 0; k < 128; k += 4) {
        float4 wv;
        wv.x = W[(size_t)(k + 0) * HID + col];
        wv.y = W[(size_t)(k + 1) * HID + col];
        wv.z = W[(size_t)(k + 2) * HID + col];
        wv.w = W[(size_t)(k + 3) * HID + col];
#pragma unroll
        for (int r = 0; r < 16; ++r) {
            float4 hv = *(const float4*)&hs[rh * 16 + r][k];
            acc[r] += hv.x * wv.x + hv.y * wv.y + hv.z * wv.z + hv.w * wv.w;
        }
    }

    float ob = 1.0f - beta;
#pragma unroll
    for (int r = 0; r < 16; ++r) {
        int rr = rh * 16 + r;
        float h = hs[rr][col];
        float v = ob * h + beta * acc[r];
        v = v > 0.f ? v : 0.f;
        H[(size_t)(row0 + rr) * HID + col] = v;
    }
}

// ---------------- final projection ----------------

__global__ __launch_bounds__(256) void final_kernel(
    const float* __restrict__ x, const float* __restrict__ Wout,
    const float* __restrict__ bout, float* __restrict__ out) {
    int node = blockIdx.x * 4 + (threadIdx.x >> 6);
    int lane = threadIdx.x & 63;
    const float2* xr = (const float2*)(x + (size_t)node * HID);
    const float2* wr = (const float2*)Wout;
    float2 a = xr[lane], w = wr[lane];
    float v = a.x * w.x + a.y * w.y;
#pragma unroll
    for (int off = 32; off; off >>= 1) v += __shfl_down(v, off, 64);
    if (lane == 0) out[node] = v + bout[0];
}

// ---------------- host ----------------

extern "C" void kernel_launch(void* const* d_in, const int* in_sizes, int n_in,
                              void* d_out, int out_size, void* d_ws, size_t ws_size,
                              hipStream_t stream) {
    const float* x_in     = (const float*)d_in[0];
    const int*   ei       = (const int*)d_in[1];
    const float* W_in     = (const float*)d_in[3];
    const float* b_in     = (const float*)d_in[4];
    const float* W_layers = (const float*)d_in[5];
    const float* W_out    = (const float*)d_in[6];
    const float* b_out    = (const float*)d_in[7];
    float* out = (float*)d_out;

    const int* src = ei;
    const int* dst = ei + NE;

    char* ws = (char*)d_ws;
    size_t off = 0;
    auto alloc = [&](size_t bytes) {
        size_t p = off;
        off = (off + bytes + 255) & ~(size_t)255;
        return p;
    };
    int*   deg     = (int*)(ws + alloc((size_t)NN * 4));
    float* dinv    = (float*)(ws + alloc((size_t)NN * 4));
    int*   row_ptr = (int*)(ws + alloc((size_t)(NN + 1) * 4));
    int*   cursor  = (int*)(ws + alloc((size_t)NN * 4));
    int*   col     = (int*)(ws + alloc((size_t)NE * 4));
    float* val     = (float*)(ws + alloc((size_t)NE * 4));
    float* x0      = (float*)(ws + alloc((size_t)NN * HID * 4));
    float* bufA    = (float*)(ws + alloc((size_t)NN * HID * 4));
    float* bufB    = (float*)(ws + alloc((size_t)NN * HID * 4));

    hipMemsetAsync(deg, 0, (size_t)NN * 4, stream);

    deg_count_kernel<<<NE / 256, 256, 0, stream>>>(dst, deg);
    dinv_kernel<<<(NN + 255) / 256, 256, 0, stream>>>(deg, dinv);
    scan_kernel<<<1, 1024, 0, stream>>>(deg, row_ptr, cursor);
    fill_kernel<<<NE / 256, 256, 0, stream>>>(src, dst, dinv, cursor, col, val);

    init_gemm_kernel<<<NN / 32, 256, 0, stream>>>(x_in, W_in, b_in, bufA, x0);

    float* cur = bufA;
    float* nxt = bufB;
    for (int l = 0; l < N_LAYERS; ++l) {
        agg_kernel<<<NN / 4, 256, 0, stream>>>(cur, x0, row_ptr, col, val, dinv, nxt);
        float beta = logf(0.5f / (float)(l + 1) + 1.0f);
        layer_gemm_kernel<<<NN / 32, 256, 0, stream>>>(nxt, W_layers + (size_t)l * HID * HID, beta);
        float* t = cur; cur = nxt; nxt = t;
    }

    final_kernel<<<NN / 4, 256, 0, stream>>>(cur, W_out, b_out, out);
}

// Round 2
// 1916.208 us; speedup vs baseline: 1.4304x; 1.4304x over previous
//
#include <hip/hip_runtime.h>
#include <math.h>

#define NN 100000
#define NE 1600000
#define IN_DIM 512
#define HID 128
#define N_LAYERS 8
#define NB 98               // ceil(NN/1024)

// ---------------- CSR build ----------------

__global__ void deg_count_kernel(const int* __restrict__ dst, int* __restrict__ deg) {
    int e = blockIdx.x * blockDim.x + threadIdx.x;
    if (e < NE) atomicAdd(&deg[dst[e]], 1);
}

__global__ void dinv_kernel(const int* __restrict__ deg, float* __restrict__ dinv,
                            int* __restrict__ row_ptr) {
    int i = blockIdx.x * blockDim.x + threadIdx.x;
    if (i < NN) dinv[i] = rsqrtf((float)(deg[i] + 1));   // +1 self loop
    if (i == 0) row_ptr[NN] = NE;
}

__global__ void scan1_kernel(const int* __restrict__ deg, int* __restrict__ bsum) {
    __shared__ int s[16];
    int gi = blockIdx.x * 1024 + threadIdx.x;
    int r = (gi < NN) ? deg[gi] : 0;
    for (int off = 32; off; off >>= 1) r += __shfl_down(r, off, 64);
    if ((threadIdx.x & 63) == 0) s[threadIdx.x >> 6] = r;
    __syncthreads();
    if (threadIdx.x == 0) {
        int t = 0;
        for (int i = 0; i < 16; ++i) t += s[i];
        bsum[blockIdx.x] = t;
    }
}

__global__ void scan2_kernel(const int* __restrict__ bsum, int* __restrict__ boff) {
    __shared__ int s[128];
    int tid = threadIdx.x;
    int v = (tid < NB) ? bsum[tid] : 0;
    s[tid] = v;
    __syncthreads();
    for (int off = 1; off < 128; off <<= 1) {
        int t = (tid >= off) ? s[tid - off] : 0;
        __syncthreads();
        s[tid] += t;
        __syncthreads();
    }
    if (tid < NB) boff[tid] = s[tid] - v;   // exclusive
}

__global__ void scan3_kernel(const int* __restrict__ deg, const int* __restrict__ boff,
                             int* __restrict__ row_ptr, int* __restrict__ cursor) {
    __shared__ int s[1024];
    int tid = threadIdx.x;
    int gi = blockIdx.x * 1024 + tid;
    int v = (gi < NN) ? deg[gi] : 0;
    s[tid] = v;
    __syncthreads();
    for (int off = 1; off < 1024; off <<= 1) {
        int t = (tid >= off) ? s[tid - off] : 0;
        __syncthreads();
        s[tid] += t;
        __syncthreads();
    }
    if (gi < NN) {
        int o = boff[blockIdx.x] + s[tid] - v;
        row_ptr[gi] = o;
        cursor[gi]  = o;
    }
}

__global__ void fill_kernel(const int* __restrict__ src, const int* __restrict__ dst,
                            const float* __restrict__ dinv, int* __restrict__ cursor,
                            int* __restrict__ col, float* __restrict__ val) {
    int e = blockIdx.x * blockDim.x + threadIdx.x;
    if (e < NE) {
        int s = src[e], d = dst[e];
        int pos = atomicAdd(&cursor[d], 1);
        col[pos] = s;
        val[pos] = dinv[s] * dinv[d];
    }
}

// ---------------- tiled fp32 GEMMs: 8x8 per-thread register tiles ----------------
// A staged k-major (conflict-free reads), W staged with even/odd granule perm.

#define BM 128
#define BK 32

__global__ __launch_bounds__(256) void init_gemm_kernel(
    const float* __restrict__ x, const float* __restrict__ W,
    const float* __restrict__ b, float* __restrict__ out, float* __restrict__ x0) {
    __shared__ float As[BK][BM];
    __shared__ float Ws[BK][HID];
    int tid = threadIdx.x;
    int rg = tid >> 4, cg = tid & 15;
    int r0 = rg * 8, c0 = cg * 8;
    int row0 = blockIdx.x * BM;

    float acc[8][8];
#pragma unroll
    for (int r = 0; r < 8; ++r)
#pragma unroll
        for (int c = 0; c < 8; ++c) acc[r][c] = 0.f;

    for (int k0 = 0; k0 < IN_DIM; k0 += BK) {
#pragma unroll
        for (int i = 0; i < 4; ++i) {                       // A: 128 rows x 32 k
            int idx = tid + i * 256;
            int row = idx & 127;
            int k4 = (idx >> 7) * 4;
            int grow = row0 + row; if (grow >= NN) grow = NN - 1;
            float4 v = *(const float4*)&x[(size_t)grow * IN_DIM + k0 + k4];
            As[k4 + 0][row] = v.x;
            As[k4 + 1][row] = v.y;
            As[k4 + 2][row] = v.z;
            As[k4 + 3][row] = v.w;
        }
#pragma unroll
        for (int i = 0; i < 4; ++i) {                       // W: 32 k x 128 cols
            int idx = tid + i * 256;
            int k = idx >> 5;
            int g = idx & 31;
            float4 v = *(const float4*)&W[(size_t)(k0 + k) * HID + g * 4];
            int gp = (g >> 1) | ((g & 1) << 4);
            *(float4*)&Ws[k][gp * 4] = v;
        }
        __syncthreads();
#pragma unroll 4
        for (int k = 0; k < BK; ++k) {
            float4 a0 = *(const float4*)&As[k][r0];
            float4 a1 = *(const float4*)&As[k][r0 + 4];
            float4 w0 = *(const float4*)&Ws[k][cg * 4];
            float4 w1 = *(const float4*)&Ws[k][(cg + 16) * 4];
            float a[8] = {a0.x, a0.y, a0.z, a0.w, a1.x, a1.y, a1.z, a1.w};
            float w[8] = {w0.x, w0.y, w0.z, w0.w, w1.x, w1.y, w1.z, w1.w};
#pragma unroll
            for (int r = 0; r < 8; ++r)
#pragma unroll
                for (int c = 0; c < 8; ++c) acc[r][c] += a[r] * w[c];
        }
        __syncthreads();
    }

    float4 b0 = *(const float4*)&b[c0];
    float4 b1 = *(const float4*)&b[c0 + 4];
    float bias[8] = {b0.x, b0.y, b0.z, b0.w, b1.x, b1.y, b1.z, b1.w};
#pragma unroll
    for (int r = 0; r < 8; ++r) {
        int grow = row0 + r0 + r;
        if (grow < NN) {
            float4 v0, v1;
            v0.x = acc[r][0] + bias[0]; v0.y = acc[r][1] + bias[1];
            v0.z = acc[r][2] + bias[2]; v0.w = acc[r][3] + bias[3];
            v1.x = acc[r][4] + bias[4]; v1.y = acc[r][5] + bias[5];
            v1.z = acc[r][6] + bias[6]; v1.w = acc[r][7] + bias[7];
            *(float4*)&out[(size_t)grow * HID + c0]     = v0;
            *(float4*)&out[(size_t)grow * HID + c0 + 4] = v1;
            *(float4*)&x0[(size_t)grow * HID + c0]      = v0;
            *(float4*)&x0[(size_t)grow * HID + c0 + 4]  = v1;
        }
    }
}

// fused: H = relu((1-beta)*h + beta*(h @ W)), in place (each block owns its rows)
__global__ __launch_bounds__(256) void layer_gemm_kernel(
    float* __restrict__ H, const float* __restrict__ W, float beta) {
    __shared__ float As[BK][BM];
    __shared__ float Ws[BK][HID];
    int tid = threadIdx.x;
    int rg = tid >> 4, cg = tid & 15;
    int r0 = rg * 8, c0 = cg * 8;
    int row0 = blockIdx.x * BM;

    float acc[8][8];
#pragma unroll
    for (int r = 0; r < 8; ++r)
#pragma unroll
        for (int c = 0; c < 8; ++c) acc[r][c] = 0.f;

    for (int k0 = 0; k0 < HID; k0 += BK) {
#pragma unroll
        for (int i = 0; i < 4; ++i) {
            int idx = tid + i * 256;
            int row = idx & 127;
            int k4 = (idx >> 7) * 4;
            int grow = row0 + row; if (grow >= NN) grow = NN - 1;
            float4 v = *(const float4*)&H[(size_t)grow * HID + k0 + k4];
            As[k4 + 0][row] = v.x;
            As[k4 + 1][row] = v.y;
            As[k4 + 2][row] = v.z;
            As[k4 + 3][row] = v.w;
        }
#pragma unroll
        for (int i = 0; i < 4; ++i) {
            int idx = tid + i * 256;
            int k = idx >> 5;
            int g = idx & 31;
            float4 v = *(const float4*)&W[(size_t)(k0 + k) * HID + g * 4];
            int gp = (g >> 1) | ((g & 1) << 4);
            *(float4*)&Ws[k][gp * 4] = v;
        }
        __syncthreads();
#pragma unroll 4
        for (int k = 0; k < BK; ++k) {
            float4 a0 = *(const float4*)&As[k][r0];
            float4 a1 = *(const float4*)&As[k][r0 + 4];
            float4 w0 = *(const float4*)&Ws[k][cg * 4];
            float4 w1 = *(const float4*)&Ws[k][(cg + 16) * 4];
            float a[8] = {a0.x, a0.y, a0.z, a0.w, a1.x, a1.y, a1.z, a1.w};
            float w[8] = {w0.x, w0.y, w0.z, w0.w, w1.x, w1.y, w1.z, w1.w};
#pragma unroll
            for (int r = 0; r < 8; ++r)
#pragma unroll
                for (int c = 0; c < 8; ++c) acc[r][c] += a[r] * w[c];
        }
        __syncthreads();
    }

    float ob = 1.0f - beta;
#pragma unroll
    for (int r = 0; r < 8; ++r) {
        int grow = row0 + r0 + r;
        if (grow < NN) {
            float4 h0 = *(const float4*)&H[(size_t)grow * HID + c0];
            float4 h1 = *(const float4*)&H[(size_t)grow * HID + c0 + 4];
            float4 v0, v1;
            v0.x = ob * h0.x + beta * acc[r][0]; v0.y = ob * h0.y + beta * acc[r][1];
            v0.z = ob * h0.z + beta * acc[r][2]; v0.w = ob * h0.w + beta * acc[r][3];
            v1.x = ob * h1.x + beta * acc[r][4]; v1.y = ob * h1.y + beta * acc[r][5];
            v1.z = ob * h1.z + beta * acc[r][6]; v1.w = ob * h1.w + beta * acc[r][7];
            v0.x = v0.x > 0.f ? v0.x : 0.f;  v0.y = v0.y > 0.f ? v0.y : 0.f;
            v0.z = v0.z > 0.f ? v0.z : 0.f;  v0.w = v0.w > 0.f ? v0.w : 0.f;
            v1.x = v1.x > 0.f ? v1.x : 0.f;  v1.y = v1.y > 0.f ? v1.y : 0.f;
            v1.z = v1.z > 0.f ? v1.z : 0.f;  v1.w = v1.w > 0.f ? v1.w : 0.f;
            *(float4*)&H[(size_t)grow * HID + c0]     = v0;
            *(float4*)&H[(size_t)grow * HID + c0 + 4] = v1;
        }
    }
}

// ---------------- sparse aggregation: one wave per node, float4, 2 edges/wave ----------------

__global__ __launch_bounds__(256) void agg_kernel(
    const float* __restrict__ x, const float* __restrict__ x0,
    const int* __restrict__ row_ptr, const int* __restrict__ col,
    const float* __restrict__ val, const float* __restrict__ dinv,
    float* __restrict__ H) {
    int node = blockIdx.x * 4 + (threadIdx.x >> 6);
    int lane = threadIdx.x & 63;
    int half = lane >> 5, q = lane & 31;
    const float4* x4 = (const float4*)x;

    float4 acc; acc.x = acc.y = acc.z = acc.w = 0.f;
    int p1 = row_ptr[node + 1];
    int p  = row_ptr[node] + half;

    while (p + 2 < p1) {                    // 2 edges per half in flight
        int s0 = col[p];     float w0 = val[p];
        int s1 = col[p + 2]; float w1 = val[p + 2];
        float4 v0 = x4[(size_t)s0 * 32 + q];
        float4 v1 = x4[(size_t)s1 * 32 + q];
        acc.x += w0 * v0.x; acc.y += w0 * v0.y; acc.z += w0 * v0.z; acc.w += w0 * v0.w;
        acc.x += w1 * v1.x; acc.y += w1 * v1.y; acc.z += w1 * v1.z; acc.w += w1 * v1.w;
        p += 4;
    }
    if (p < p1) {
        int s = col[p]; float w = val[p];
        float4 v = x4[(size_t)s * 32 + q];
        acc.x += w * v.x; acc.y += w * v.y; acc.z += w * v.z; acc.w += w * v.w;
    }

    acc.x += __shfl_xor(acc.x, 32, 64);
    acc.y += __shfl_xor(acc.y, 32, 64);
    acc.z += __shfl_xor(acc.z, 32, 64);
    acc.w += __shfl_xor(acc.w, 32, 64);

    if (half == 0) {
        float di = dinv[node];
        float d2 = di * di;
        float4 sv = x4[(size_t)node * 32 + q];
        float4 zv = ((const float4*)x0)[(size_t)node * 32 + q];
        float4 h;
        h.x = 0.9f * (acc.x + d2 * sv.x) + 0.1f * zv.x;
        h.y = 0.9f * (acc.y + d2 * sv.y) + 0.1f * zv.y;
        h.z = 0.9f * (acc.z + d2 * sv.z) + 0.1f * zv.z;
        h.w = 0.9f * (acc.w + d2 * sv.w) + 0.1f * zv.w;
        ((float4*)H)[(size_t)node * 32 + q] = h;
    }
}

// ---------------- final projection ----------------

__global__ __launch_bounds__(256) void final_kernel(
    const float* __restrict__ x, const float* __restrict__ Wout,
    const float* __restrict__ bout, float* __restrict__ out) {
    int node = blockIdx.x * 4 + (threadIdx.x >> 6);
    int lane = threadIdx.x & 63;
    const float2* xr = (const float2*)(x + (size_t)node * HID);
    const float2* wr = (const float2*)Wout;
    float2 a = xr[lane], w = wr[lane];
    float v = a.x * w.x + a.y * w.y;
#pragma unroll
    for (int off = 32; off; off >>= 1) v += __shfl_down(v, off, 64);
    if (lane == 0) out[node] = v + bout[0];
}

// ---------------- host ----------------

extern "C" void kernel_launch(void* const* d_in, const int* in_sizes, int n_in,
                              void* d_out, int out_size, void* d_ws, size_t ws_size,
                              hipStream_t stream) {
    const float* x_in     = (const float*)d_in[0];
    const int*   ei       = (const int*)d_in[1];
    const float* W_in     = (const float*)d_in[3];
    const float* b_in     = (const float*)d_in[4];
    const float* W_layers = (const float*)d_in[5];
    const float* W_out    = (const float*)d_in[6];
    const float* b_out    = (const float*)d_in[7];
    float* out = (float*)d_out;

    const int* src = ei;
    const int* dst = ei + NE;

    char* ws = (char*)d_ws;
    size_t off = 0;
    auto alloc = [&](size_t bytes) {
        size_t p = off;
        off = (off + bytes + 255) & ~(size_t)255;
        return p;
    };
    int*   deg     = (int*)(ws + alloc((size_t)NN * 4));
    float* dinv    = (float*)(ws + alloc((size_t)NN * 4));
    int*   row_ptr = (int*)(ws + alloc((size_t)(NN + 1) * 4));
    int*   cursor  = (int*)(ws + alloc((size_t)NN * 4));
    int*   bsum    = (int*)(ws + alloc((size_t)NB * 4));
    int*   boff    = (int*)(ws + alloc((size_t)NB * 4));
    int*   col     = (int*)(ws + alloc((size_t)NE * 4));
    float* val     = (float*)(ws + alloc((size_t)NE * 4));
    float* x0      = (float*)(ws + alloc((size_t)NN * HID * 4));
    float* bufA    = (float*)(ws + alloc((size_t)NN * HID * 4));
    float* bufB    = (float*)(ws + alloc((size_t)NN * HID * 4));

    hipMemsetAsync(deg, 0, (size_t)NN * 4, stream);

    deg_count_kernel<<<NE / 256, 256, 0, stream>>>(dst, deg);
    dinv_kernel<<<(NN + 255) / 256, 256, 0, stream>>>(deg, dinv, row_ptr);
    scan1_kernel<<<NB, 1024, 0, stream>>>(deg, bsum);
    scan2_kernel<<<1, 128, 0, stream>>>(bsum, boff);
    scan3_kernel<<<NB, 1024, 0, stream>>>(deg, boff, row_ptr, cursor);
    fill_kernel<<<NE / 256, 256, 0, stream>>>(src, dst, dinv, cursor, col, val);

    int gemm_grid = (NN + BM - 1) / BM;
    init_gemm_kernel<<<gemm_grid, 256, 0, stream>>>(x_in, W_in, b_in, bufA, x0);

    float* cur = bufA;
    float* nxt = bufB;
    for (int l = 0; l < N_LAYERS; ++l) {
        agg_kernel<<<NN / 4, 256, 0, stream>>>(cur, x0, row_ptr, col, val, dinv, nxt);
        float beta = logf(0.5f / (float)(l + 1) + 1.0f);
        layer_gemm_kernel<<<gemm_grid, 256, 0, stream>>>(nxt, W_layers + (size_t)l * HID * HID, beta);
        float* t = cur; cur = nxt; nxt = t;
    }

    final_kernel<<<NN / 4, 256, 0, stream>>>(cur, W_out, b_out, out);
}

// Round 3
// 1418.149 us; speedup vs baseline: 1.9327x; 1.3512x over previous
//
#include <hip/hip_runtime.h>
#include <math.h>

#define NN 100000
#define NE 1600000
#define IN_DIM 512
#define HID 128
#define N_LAYERS 8
#define NB 98               // ceil(NN/1024)

typedef __attribute__((ext_vector_type(4))) float f32x4;
typedef __attribute__((ext_vector_type(8))) short s16x8;
typedef __attribute__((ext_vector_type(8))) _Float16 h16x8;
typedef __attribute__((ext_vector_type(2))) _Float16 h16x2;

__device__ inline unsigned short bf16_rne(float f) {
    unsigned u = __float_as_uint(f);
    return (unsigned short)((u + 0x7FFFu + ((u >> 16) & 1u)) >> 16);
}
__device__ inline void split_bf16(float f, short& hi, short& lo) {
    unsigned short h = bf16_rne(f);
    float fh = __uint_as_float((unsigned)h << 16);
    hi = (short)h;
    lo = (short)bf16_rne(f - fh);
}

// ---------------- CSR build ----------------

__global__ void deg_count_kernel(const int* __restrict__ dst, int* __restrict__ deg) {
    int e = blockIdx.x * blockDim.x + threadIdx.x;
    if (e < NE) atomicAdd(&deg[dst[e]], 1);
}

__global__ void dinv_kernel(const int* __restrict__ deg, float* __restrict__ dinv,
                            int* __restrict__ row_ptr) {
    int i = blockIdx.x * blockDim.x + threadIdx.x;
    if (i < NN) dinv[i] = rsqrtf((float)(deg[i] + 1));   // +1 self loop
    if (i == 0) row_ptr[NN] = NE;
}

__global__ void scan1_kernel(const int* __restrict__ deg, int* __restrict__ bsum) {
    __shared__ int s[16];
    int gi = blockIdx.x * 1024 + threadIdx.x;
    int r = (gi < NN) ? deg[gi] : 0;
    for (int off = 32; off; off >>= 1) r += __shfl_down(r, off, 64);
    if ((threadIdx.x & 63) == 0) s[threadIdx.x >> 6] = r;
    __syncthreads();
    if (threadIdx.x == 0) {
        int t = 0;
        for (int i = 0; i < 16; ++i) t += s[i];
        bsum[blockIdx.x] = t;
    }
}

__global__ void scan2_kernel(const int* __restrict__ bsum, int* __restrict__ boff) {
    __shared__ int s[128];
    int tid = threadIdx.x;
    int v = (tid < NB) ? bsum[tid] : 0;
    s[tid] = v;
    __syncthreads();
    for (int off = 1; off < 128; off <<= 1) {
        int t = (tid >= off) ? s[tid - off] : 0;
        __syncthreads();
        s[tid] += t;
        __syncthreads();
    }
    if (tid < NB) boff[tid] = s[tid] - v;   // exclusive
}

__global__ void scan3_kernel(const int* __restrict__ deg, const int* __restrict__ boff,
                             int* __restrict__ row_ptr, int* __restrict__ cursor) {
    __shared__ int s[1024];
    int tid = threadIdx.x;
    int gi = blockIdx.x * 1024 + tid;
    int v = (gi < NN) ? deg[gi] : 0;
    s[tid] = v;
    __syncthreads();
    for (int off = 1; off < 1024; off <<= 1) {
        int t = (tid >= off) ? s[tid - off] : 0;
        __syncthreads();
        s[tid] += t;
        __syncthreads();
    }
    if (gi < NN) {
        int o = boff[blockIdx.x] + s[tid] - v;
        row_ptr[gi] = o;
        cursor[gi]  = o;
    }
}

__global__ void fill_kernel(const int* __restrict__ src, const int* __restrict__ dst,
                            const float* __restrict__ dinv, int* __restrict__ cursor,
                            int* __restrict__ col, float* __restrict__ val) {
    int e = blockIdx.x * blockDim.x + threadIdx.x;
    if (e < NE) {
        int s = src[e], d = dst[e];
        int pos = atomicAdd(&cursor[d], 1);
        col[pos] = s;
        val[pos] = dinv[s] * dinv[d];
    }
}

// ---------------- W prep: split-bf16, MFMA B-fragment order ----------------
// B-frag element for (n,kk): B[k = kk*32 + (lane>>4)*8 + j][col = n*16 + (lane&15)]
// stored at [ (n*KK + kk)*64 + lane ]*8 + j  (short), hi and lo separate.

__global__ void wprep_init_kernel(const float* __restrict__ W,
                                  short* __restrict__ Bhi, short* __restrict__ Blo) {
    int t = blockIdx.x * 256 + threadIdx.x;     // 8 * 16 * 64 = 8192 threads
    if (t >= 8 * 16 * 64) return;
    int lane = t & 63, nkk = t >> 6;
    int n = nkk >> 4, kk = nkk & 15;
    int scol = n * 16 + (lane & 15);
    int sr0 = kk * 32 + (lane >> 4) * 8;
#pragma unroll
    for (int j = 0; j < 8; ++j) {
        float w = W[(size_t)(sr0 + j) * HID + scol];
        short hi, lo; split_bf16(w, hi, lo);
        Bhi[(size_t)t * 8 + j] = hi;
        Blo[(size_t)t * 8 + j] = lo;
    }
}

__global__ void wprep_layers_kernel(const float* __restrict__ WL,
                                    short* __restrict__ Bhi, short* __restrict__ Blo) {
    int t = blockIdx.x * 256 + threadIdx.x;     // 8 layers * 8*4*64 = 16384 threads
    if (t >= N_LAYERS * 8 * 4 * 64) return;
    int layer = t >> 11;
    int r = t & 2047;
    int lane = r & 63, nkk = r >> 6;
    int n = nkk >> 2, kk = nkk & 3;
    const float* W = WL + (size_t)layer * HID * HID;
    int scol = n * 16 + (lane & 15);
    int sr0 = kk * 32 + (lane >> 4) * 8;
#pragma unroll
    for (int j = 0; j < 8; ++j) {
        float w = W[(size_t)(sr0 + j) * HID + scol];
        short hi, lo; split_bf16(w, hi, lo);
        Bhi[(size_t)t * 8 + j] = hi;
        Blo[(size_t)t * 8 + j] = lo;
    }
}

// ---------------- init projection: x[NN][512] @ W[512][128] + b -> fp16 ----------------
// 4 waves/block, 32 rows/wave, 128 rows/block. No LDS; A frags from global, split in reg.

__global__ __launch_bounds__(256) void init_mfma_kernel(
    const float* __restrict__ x, const s16x8* __restrict__ Bhi, const s16x8* __restrict__ Blo,
    const float* __restrict__ b, _Float16* __restrict__ cur, _Float16* __restrict__ x0h) {
    int lane = threadIdx.x & 63, wid = threadIdx.x >> 6;
    int row0w = blockIdx.x * 128 + wid * 32;
    int rsel = lane & 15, ksel = lane >> 4;

    f32x4 acc[2][8];
#pragma unroll
    for (int m = 0; m < 2; ++m)
#pragma unroll
        for (int n = 0; n < 8; ++n) acc[m][n] = (f32x4){0.f, 0.f, 0.f, 0.f};

    for (int kk = 0; kk < 16; ++kk) {
        s16x8 ahi[2], alo[2];
#pragma unroll
        for (int m = 0; m < 2; ++m) {
            int row = row0w + 16 * m + rsel; if (row >= NN) row = NN - 1;
            const float* p = x + (size_t)row * IN_DIM + kk * 32 + ksel * 8;
            float4 v0 = *(const float4*)p;
            float4 v1 = *(const float4*)(p + 4);
            float vf[8] = {v0.x, v0.y, v0.z, v0.w, v1.x, v1.y, v1.z, v1.w};
#pragma unroll
            for (int j = 0; j < 8; ++j) {
                short hi, lo; split_bf16(vf[j], hi, lo);
                ahi[m][j] = hi; alo[m][j] = lo;
            }
        }
#pragma unroll
        for (int n = 0; n < 8; ++n) {
            s16x8 bh = Bhi[(n * 16 + kk) * 64 + lane];
            s16x8 bl = Blo[(n * 16 + kk) * 64 + lane];
#pragma unroll
            for (int m = 0; m < 2; ++m) {
                acc[m][n] = __builtin_amdgcn_mfma_f32_16x16x32_bf16(ahi[m], bh, acc[m][n], 0, 0, 0);
                acc[m][n] = __builtin_amdgcn_mfma_f32_16x16x32_bf16(alo[m], bh, acc[m][n], 0, 0, 0);
                acc[m][n] = __builtin_amdgcn_mfma_f32_16x16x32_bf16(ahi[m], bl, acc[m][n], 0, 0, 0);
            }
        }
    }

#pragma unroll
    for (int m = 0; m < 2; ++m)
#pragma unroll
        for (int n = 0; n < 8; ++n) {
            int col = n * 16 + rsel;
            float bias = b[col];
#pragma unroll
            for (int r = 0; r < 4; ++r) {
                int row = row0w + 16 * m + ksel * 4 + r;
                if (row < NN) {
                    float v = acc[m][n][r] + bias;
                    _Float16 hv = (_Float16)v;
                    cur[(size_t)row * HID + col] = hv;
                    x0h[(size_t)row * HID + col] = hv;
                }
            }
        }
}

// ---------------- layer GEMM: cur = relu((1-b)*H + b*(H @ W)) -> fp16 ----------------

__global__ __launch_bounds__(256) void layer_mfma_kernel(
    const float* __restrict__ H, const s16x8* __restrict__ Bhi, const s16x8* __restrict__ Blo,
    float beta, _Float16* __restrict__ cur) {
    int lane = threadIdx.x & 63, wid = threadIdx.x >> 6;
    int row0w = blockIdx.x * 128 + wid * 32;
    int rsel = lane & 15, ksel = lane >> 4;

    s16x8 ahi[2][4], alo[2][4];
#pragma unroll
    for (int m = 0; m < 2; ++m) {
        int row = row0w + 16 * m + rsel; if (row >= NN) row = NN - 1;
        const float* rp = H + (size_t)row * HID + ksel * 8;
#pragma unroll
        for (int kk = 0; kk < 4; ++kk) {
            float4 v0 = *(const float4*)(rp + kk * 32);
            float4 v1 = *(const float4*)(rp + kk * 32 + 4);
            float vf[8] = {v0.x, v0.y, v0.z, v0.w, v1.x, v1.y, v1.z, v1.w};
#pragma unroll
            for (int j = 0; j < 8; ++j) {
                short hi, lo; split_bf16(vf[j], hi, lo);
                ahi[m][kk][j] = hi; alo[m][kk][j] = lo;
            }
        }
    }

    f32x4 acc[2][8];
#pragma unroll
    for (int m = 0; m < 2; ++m)
#pragma unroll
        for (int n = 0; n < 8; ++n) acc[m][n] = (f32x4){0.f, 0.f, 0.f, 0.f};

#pragma unroll
    for (int n = 0; n < 8; ++n)
#pragma unroll
        for (int kk = 0; kk < 4; ++kk) {
            s16x8 bh = Bhi[(n * 4 + kk) * 64 + lane];
            s16x8 bl = Blo[(n * 4 + kk) * 64 + lane];
#pragma unroll
            for (int m = 0; m < 2; ++m) {
                acc[m][n] = __builtin_amdgcn_mfma_f32_16x16x32_bf16(ahi[m][kk], bh, acc[m][n], 0, 0, 0);
                acc[m][n] = __builtin_amdgcn_mfma_f32_16x16x32_bf16(alo[m][kk], bh, acc[m][n], 0, 0, 0);
                acc[m][n] = __builtin_amdgcn_mfma_f32_16x16x32_bf16(ahi[m][kk], bl, acc[m][n], 0, 0, 0);
            }
        }

    float ob = 1.0f - beta;
#pragma unroll
    for (int m = 0; m < 2; ++m)
#pragma unroll
        for (int n = 0; n < 8; ++n) {
            int col = n * 16 + rsel;
#pragma unroll
            for (int r = 0; r < 4; ++r) {
                int row = row0w + 16 * m + ksel * 4 + r;
                if (row < NN) {
                    float h = H[(size_t)row * HID + col];
                    float v = ob * h + beta * acc[m][n][r];
                    v = v > 0.f ? v : 0.f;
                    cur[(size_t)row * HID + col] = (_Float16)v;
                }
            }
        }
}

// ---------------- sparse aggregation: fp16 gathers, 16-lane groups, 4 edges/wave ----------------

__global__ __launch_bounds__(256) void agg16_kernel(
    const _Float16* __restrict__ x, const _Float16* __restrict__ x0,
    const int* __restrict__ row_ptr, const int* __restrict__ col,
    const float* __restrict__ val, const float* __restrict__ dinv,
    float* __restrict__ H) {
    int node = blockIdx.x * 4 + (threadIdx.x >> 6);
    int lane = threadIdx.x & 63;
    int g = lane >> 4, q = lane & 15;
    const h16x8* x8 = (const h16x8*)x;

    float acc[8];
#pragma unroll
    for (int j = 0; j < 8; ++j) acc[j] = 0.f;

    int p1 = row_ptr[node + 1];
    int p  = row_ptr[node] + g;
    for (; p + 4 < p1; p += 8) {                 // 2 edges per group in flight
        int s0 = col[p];     float w0 = val[p];
        int s1 = col[p + 4]; float w1 = val[p + 4];
        h16x8 v0 = x8[(size_t)s0 * 16 + q];
        h16x8 v1 = x8[(size_t)s1 * 16 + q];
#pragma unroll
        for (int j = 0; j < 8; ++j) acc[j] += w0 * (float)v0[j] + w1 * (float)v1[j];
    }
    if (p < p1) {
        int s = col[p]; float w = val[p];
        h16x8 v = x8[(size_t)s * 16 + q];
#pragma unroll
        for (int j = 0; j < 8; ++j) acc[j] += w * (float)v[j];
    }

#pragma unroll
    for (int j = 0; j < 8; ++j) {
        acc[j] += __shfl_xor(acc[j], 16, 64);
        acc[j] += __shfl_xor(acc[j], 32, 64);
    }

    if (g == 0) {
        float di = dinv[node], d2 = di * di;
        h16x8 sv = x8[(size_t)node * 16 + q];
        h16x8 zv = ((const h16x8*)x0)[(size_t)node * 16 + q];
        float o[8];
#pragma unroll
        for (int j = 0; j < 8; ++j)
            o[j] = 0.9f * (acc[j] + d2 * (float)sv[j]) + 0.1f * (float)zv[j];
        float* hp = H + (size_t)node * HID + q * 8;
        float4 a0 = {o[0], o[1], o[2], o[3]};
        float4 a1 = {o[4], o[5], o[6], o[7]};
        *(float4*)hp = a0;
        *(float4*)(hp + 4) = a1;
    }
}

// ---------------- final projection ----------------

__global__ __launch_bounds__(256) void final16_kernel(
    const _Float16* __restrict__ x, const float* __restrict__ Wout,
    const float* __restrict__ bout, float* __restrict__ out) {
    int node = blockIdx.x * 4 + (threadIdx.x >> 6);
    int lane = threadIdx.x & 63;
    h16x2 a = ((const h16x2*)x)[(size_t)node * 64 + lane];
    float2 w = ((const float2*)Wout)[lane];
    float v = (float)a[0] * w.x + (float)a[1] * w.y;
#pragma unroll
    for (int off = 32; off; off >>= 1) v += __shfl_down(v, off, 64);
    if (lane == 0) out[node] = v + bout[0];
}

// ---------------- host ----------------

extern "C" void kernel_launch(void* const* d_in, const int* in_sizes, int n_in,
                              void* d_out, int out_size, void* d_ws, size_t ws_size,
                              hipStream_t stream) {
    const float* x_in     = (const float*)d_in[0];
    const int*   ei       = (const int*)d_in[1];
    const float* W_in     = (const float*)d_in[3];
    const float* b_in     = (const float*)d_in[4];
    const float* W_layers = (const float*)d_in[5];
    const float* W_out    = (const float*)d_in[6];
    const float* b_out    = (const float*)d_in[7];
    float* out = (float*)d_out;

    const int* src = ei;
    const int* dst = ei + NE;

    char* ws = (char*)d_ws;
    size_t off = 0;
    auto alloc = [&](size_t bytes) {
        size_t p = off;
        off = (off + bytes + 255) & ~(size_t)255;
        return p;
    };
    int*   deg     = (int*)(ws + alloc((size_t)NN * 4));
    float* dinv    = (float*)(ws + alloc((size_t)NN * 4));
    int*   row_ptr = (int*)(ws + alloc((size_t)(NN + 1) * 4));
    int*   cursor  = (int*)(ws + alloc((size_t)NN * 4));
    int*   bsum    = (int*)(ws + alloc((size_t)NB * 4));
    int*   boff    = (int*)(ws + alloc((size_t)NB * 4));
    int*   col     = (int*)(ws + alloc((size_t)NE * 4));
    float* val     = (float*)(ws + alloc((size_t)NE * 4));
    _Float16* x0h  = (_Float16*)(ws + alloc((size_t)NN * HID * 2));
    _Float16* cur  = (_Float16*)(ws + alloc((size_t)NN * HID * 2));
    float* H       = (float*)(ws + alloc((size_t)NN * HID * 4));
    short* Bhi0    = (short*)(ws + alloc((size_t)IN_DIM * HID * 2));
    short* Blo0    = (short*)(ws + alloc((size_t)IN_DIM * HID * 2));
    short* BhiL    = (short*)(ws + alloc((size_t)N_LAYERS * HID * HID * 2));
    short* BloL    = (short*)(ws + alloc((size_t)N_LAYERS * HID * HID * 2));

    hipMemsetAsync(deg, 0, (size_t)NN * 4, stream);

    deg_count_kernel<<<NE / 256, 256, 0, stream>>>(dst, deg);
    dinv_kernel<<<(NN + 255) / 256, 256, 0, stream>>>(deg, dinv, row_ptr);
    scan1_kernel<<<NB, 1024, 0, stream>>>(deg, bsum);
    scan2_kernel<<<1, 128, 0, stream>>>(bsum, boff);
    scan3_kernel<<<NB, 1024, 0, stream>>>(deg, boff, row_ptr, cursor);
    fill_kernel<<<NE / 256, 256, 0, stream>>>(src, dst, dinv, cursor, col, val);

    wprep_init_kernel<<<32, 256, 0, stream>>>(W_in, Bhi0, Blo0);
    wprep_layers_kernel<<<64, 256, 0, stream>>>(W_layers, BhiL, BloL);

    int gemm_grid = (NN + 127) / 128;
    init_mfma_kernel<<<gemm_grid, 256, 0, stream>>>(
        x_in, (const s16x8*)Bhi0, (const s16x8*)Blo0, b_in, cur, x0h);

    for (int l = 0; l < N_LAYERS; ++l) {
        agg16_kernel<<<NN / 4, 256, 0, stream>>>(cur, x0h, row_ptr, col, val, dinv, H);
        float beta = logf(0.5f / (float)(l + 1) + 1.0f);
        layer_mfma_kernel<<<gemm_grid, 256, 0, stream>>>(
            H, (const s16x8*)(BhiL + (size_t)l * HID * HID),
            (const s16x8*)(BloL + (size_t)l * HID * HID), beta, cur);
    }

    final16_kernel<<<NN / 4, 256, 0, stream>>>(cur, W_out, b_out, out);
}

// Round 4
// 1334.296 us; speedup vs baseline: 2.0542x; 1.0628x over previous
//
#include <hip/hip_runtime.h>
#include <math.h>

#define NN 100000
#define NE 1600000
#define IN_DIM 512
#define HID 128
#define N_LAYERS 8
#define NB 98               // ceil(NN/1024)
#define PADMAX 3200000      // NE + 15*NN + slack

typedef __attribute__((ext_vector_type(4))) float f32x4;
typedef __attribute__((ext_vector_type(8))) short s16x8;
typedef __attribute__((ext_vector_type(8))) _Float16 h16x8;
typedef __attribute__((ext_vector_type(2))) _Float16 h16x2;

__device__ inline unsigned short bf16_rne(float f) {
    unsigned u = __float_as_uint(f);
    return (unsigned short)((u + 0x7FFFu + ((u >> 16) & 1u)) >> 16);
}
__device__ inline void split_bf16(float f, short& hi, short& lo) {
    unsigned short h = bf16_rne(f);
    float fh = __uint_as_float((unsigned)h << 16);
    hi = (short)h;
    lo = (short)bf16_rne(f - fh);
}
__device__ inline float bf16_f32(short s) {
    return __uint_as_float(((unsigned)(unsigned short)s) << 16);
}

// ---------------- CSR build (rows padded to multiples of 16) ----------------

__global__ void deg_count_kernel(const int* __restrict__ dst, int* __restrict__ deg) {
    int e = blockIdx.x * blockDim.x + threadIdx.x;
    if (e < NE) atomicAdd(&deg[dst[e]], 1);
}

__global__ void dinv_kernel(const int* __restrict__ deg, float* __restrict__ dinv) {
    int i = blockIdx.x * blockDim.x + threadIdx.x;
    if (i < NN) dinv[i] = rsqrtf((float)(deg[i] + 1));   // +1 self loop
}

__global__ void scan1_kernel(const int* __restrict__ deg, int* __restrict__ bsum) {
    __shared__ int s[16];
    int gi = blockIdx.x * 1024 + threadIdx.x;
    int d = (gi < NN) ? deg[gi] : 0;
    int r = (d + 15) & ~15;                              // padded capacity
    for (int off = 32; off; off >>= 1) r += __shfl_down(r, off, 64);
    if ((threadIdx.x & 63) == 0) s[threadIdx.x >> 6] = r;
    __syncthreads();
    if (threadIdx.x == 0) {
        int t = 0;
        for (int i = 0; i < 16; ++i) t += s[i];
        bsum[blockIdx.x] = t;
    }
}

__global__ void scan2_kernel(const int* __restrict__ bsum, int* __restrict__ boff,
                             int* __restrict__ row_ptr) {
    __shared__ int s[128];
    int tid = threadIdx.x;
    int v = (tid < NB) ? bsum[tid] : 0;
    s[tid] = v;
    __syncthreads();
    for (int off = 1; off < 128; off <<= 1) {
        int t = (tid >= off) ? s[tid - off] : 0;
        __syncthreads();
        s[tid] += t;
        __syncthreads();
    }
    if (tid < NB) boff[tid] = s[tid] - v;   // exclusive
    if (tid == NB - 1) row_ptr[NN] = s[tid];
}

__global__ void scan3_kernel(const int* __restrict__ deg, const int* __restrict__ boff,
                             int* __restrict__ row_ptr, int* __restrict__ cursor) {
    __shared__ int s[1024];
    int tid = threadIdx.x;
    int gi = blockIdx.x * 1024 + tid;
    int d = (gi < NN) ? deg[gi] : 0;
    int v = (d + 15) & ~15;
    s[tid] = v;
    __syncthreads();
    for (int off = 1; off < 1024; off <<= 1) {
        int t = (tid >= off) ? s[tid - off] : 0;
        __syncthreads();
        s[tid] += t;
        __syncthreads();
    }
    if (gi < NN) {
        int o = boff[blockIdx.x] + s[tid] - v;
        row_ptr[gi] = o;
        cursor[gi]  = o;
    }
}

__global__ void fill_kernel(const int* __restrict__ src, const int* __restrict__ dst,
                            const float* __restrict__ dinv, int* __restrict__ cursor,
                            int* __restrict__ col, float* __restrict__ val) {
    int e = blockIdx.x * blockDim.x + threadIdx.x;
    if (e < NE) {
        int s = src[e], d = dst[e];
        int pos = atomicAdd(&cursor[d], 1);
        col[pos] = s;
        val[pos] = dinv[s] * dinv[d];
    }
}

// ---------------- W prep: split-bf16, MFMA B-fragment order ----------------

__global__ void wprep_init_kernel(const float* __restrict__ W,
                                  short* __restrict__ Bhi, short* __restrict__ Blo) {
    int t = blockIdx.x * 256 + threadIdx.x;     // 8 * 16 * 64 = 8192 threads
    if (t >= 8 * 16 * 64) return;
    int lane = t & 63, nkk = t >> 6;
    int n = nkk >> 4, kk = nkk & 15;
    int scol = n * 16 + (lane & 15);
    int sr0 = kk * 32 + (lane >> 4) * 8;
#pragma unroll
    for (int j = 0; j < 8; ++j) {
        float w = W[(size_t)(sr0 + j) * HID + scol];
        short hi, lo; split_bf16(w, hi, lo);
        Bhi[(size_t)t * 8 + j] = hi;
        Blo[(size_t)t * 8 + j] = lo;
    }
}

__global__ void wprep_layers_kernel(const float* __restrict__ WL,
                                    short* __restrict__ Bhi, short* __restrict__ Blo) {
    int t = blockIdx.x * 256 + threadIdx.x;     // 8 layers * 8*4*64 = 16384 threads
    if (t >= N_LAYERS * 8 * 4 * 64) return;
    int layer = t >> 11;
    int r = t & 2047;
    int lane = r & 63, nkk = r >> 6;
    int n = nkk >> 2, kk = nkk & 3;
    const float* W = WL + (size_t)layer * HID * HID;
    int scol = n * 16 + (lane & 15);
    int sr0 = kk * 32 + (lane >> 4) * 8;
#pragma unroll
    for (int j = 0; j < 8; ++j) {
        float w = W[(size_t)(sr0 + j) * HID + scol];
        short hi, lo; split_bf16(w, hi, lo);
        Bhi[(size_t)t * 8 + j] = hi;
        Blo[(size_t)t * 8 + j] = lo;
    }
}

// ---------------- init projection: x[NN][512] @ W[512][128] + b -> fp16 ----------------
// software-pipelined: kk+1 x-fragments prefetched during kk's MFMA block

__global__ __launch_bounds__(256) void init_mfma_kernel(
    const float* __restrict__ x, const s16x8* __restrict__ Bhi, const s16x8* __restrict__ Blo,
    const float* __restrict__ b, _Float16* __restrict__ cur, _Float16* __restrict__ x0h) {
    int lane = threadIdx.x & 63, wid = threadIdx.x >> 6;
    int row0w = blockIdx.x * 128 + wid * 32;
    int rsel = lane & 15, ksel = lane >> 4;

    int rowm[2];
    const float* rp[2];
#pragma unroll
    for (int m = 0; m < 2; ++m) {
        int row = row0w + 16 * m + rsel; if (row >= NN) row = NN - 1;
        rowm[m] = row;
        rp[m] = x + (size_t)row * IN_DIM + ksel * 8;
    }

    f32x4 acc[2][8];
#pragma unroll
    for (int m = 0; m < 2; ++m)
#pragma unroll
        for (int n = 0; n < 8; ++n) acc[m][n] = (f32x4){0.f, 0.f, 0.f, 0.f};

    float4 cva[2], cvb[2];
#pragma unroll
    for (int m = 0; m < 2; ++m) {
        cva[m] = *(const float4*)(rp[m]);
        cvb[m] = *(const float4*)(rp[m] + 4);
    }

#pragma unroll
    for (int kk = 0; kk < 16; ++kk) {
        float4 nva[2], nvb[2];
        if (kk < 15) {
#pragma unroll
            for (int m = 0; m < 2; ++m) {
                nva[m] = *(const float4*)(rp[m] + (kk + 1) * 32);
                nvb[m] = *(const float4*)(rp[m] + (kk + 1) * 32 + 4);
            }
        }
        s16x8 ahi[2], alo[2];
#pragma unroll
        for (int m = 0; m < 2; ++m) {
            float vf[8] = {cva[m].x, cva[m].y, cva[m].z, cva[m].w,
                           cvb[m].x, cvb[m].y, cvb[m].z, cvb[m].w};
#pragma unroll
            for (int j = 0; j < 8; ++j) {
                short hi, lo; split_bf16(vf[j], hi, lo);
                ahi[m][j] = hi; alo[m][j] = lo;
            }
        }
#pragma unroll
        for (int n = 0; n < 8; ++n) {
            s16x8 bh = Bhi[(n * 16 + kk) * 64 + lane];
            s16x8 bl = Blo[(n * 16 + kk) * 64 + lane];
#pragma unroll
            for (int m = 0; m < 2; ++m) {
                acc[m][n] = __builtin_amdgcn_mfma_f32_16x16x32_bf16(ahi[m], bh, acc[m][n], 0, 0, 0);
                acc[m][n] = __builtin_amdgcn_mfma_f32_16x16x32_bf16(alo[m], bh, acc[m][n], 0, 0, 0);
                acc[m][n] = __builtin_amdgcn_mfma_f32_16x16x32_bf16(ahi[m], bl, acc[m][n], 0, 0, 0);
            }
        }
        if (kk < 15) {
#pragma unroll
            for (int m = 0; m < 2; ++m) { cva[m] = nva[m]; cvb[m] = nvb[m]; }
        }
    }

#pragma unroll
    for (int m = 0; m < 2; ++m)
#pragma unroll
        for (int n = 0; n < 8; ++n) {
            int col = n * 16 + rsel;
            float bias = b[col];
#pragma unroll
            for (int r = 0; r < 4; ++r) {
                int row = row0w + 16 * m + ksel * 4 + r;
                if (row < NN) {
                    float v = acc[m][n][r] + bias;
                    _Float16 hv = (_Float16)v;
                    cur[(size_t)row * HID + col] = hv;
                    x0h[(size_t)row * HID + col] = hv;
                }
            }
        }
}

// ---------------- layer GEMM: cur = relu((1-b)*H + b*(H @ W)) -> fp16 ----------------
// A fragments load directly from split-bf16 planes (no VALU split)

__global__ __launch_bounds__(256) void layer_mfma_kernel(
    const short* __restrict__ Hhi, const short* __restrict__ Hlo,
    const s16x8* __restrict__ Bhi, const s16x8* __restrict__ Blo,
    float beta, _Float16* __restrict__ cur) {
    int lane = threadIdx.x & 63, wid = threadIdx.x >> 6;
    int row0w = blockIdx.x * 128 + wid * 32;
    int rsel = lane & 15, ksel = lane >> 4;

    s16x8 ahi[2][4], alo[2][4];
#pragma unroll
    for (int m = 0; m < 2; ++m) {
        int row = row0w + 16 * m + rsel; if (row >= NN) row = NN - 1;
        const short* hp = Hhi + (size_t)row * HID + ksel * 8;
        const short* lp = Hlo + (size_t)row * HID + ksel * 8;
#pragma unroll
        for (int kk = 0; kk < 4; ++kk) {
            ahi[m][kk] = *(const s16x8*)(hp + kk * 32);
            alo[m][kk] = *(const s16x8*)(lp + kk * 32);
        }
    }

    f32x4 acc[2][8];
#pragma unroll
    for (int m = 0; m < 2; ++m)
#pragma unroll
        for (int n = 0; n < 8; ++n) acc[m][n] = (f32x4){0.f, 0.f, 0.f, 0.f};

#pragma unroll
    for (int n = 0; n < 8; ++n)
#pragma unroll
        for (int kk = 0; kk < 4; ++kk) {
            s16x8 bh = Bhi[(n * 4 + kk) * 64 + lane];
            s16x8 bl = Blo[(n * 4 + kk) * 64 + lane];
#pragma unroll
            for (int m = 0; m < 2; ++m) {
                acc[m][n] = __builtin_amdgcn_mfma_f32_16x16x32_bf16(ahi[m][kk], bh, acc[m][n], 0, 0, 0);
                acc[m][n] = __builtin_amdgcn_mfma_f32_16x16x32_bf16(alo[m][kk], bh, acc[m][n], 0, 0, 0);
                acc[m][n] = __builtin_amdgcn_mfma_f32_16x16x32_bf16(ahi[m][kk], bl, acc[m][n], 0, 0, 0);
            }
        }

    float ob = 1.0f - beta;
#pragma unroll
    for (int m = 0; m < 2; ++m)
#pragma unroll
        for (int n = 0; n < 8; ++n) {
            int col = n * 16 + rsel;
#pragma unroll
            for (int r = 0; r < 4; ++r) {
                int row = row0w + 16 * m + ksel * 4 + r;
                if (row < NN) {
                    size_t o = (size_t)row * HID + col;
                    float h = bf16_f32(Hhi[o]) + bf16_f32(Hlo[o]);
                    float v = ob * h + beta * acc[m][n][r];
                    v = v > 0.f ? v : 0.f;
                    cur[o] = (_Float16)v;
                }
            }
        }
}

// ---------------- sparse aggregation: padded CSR, 16 gathers in flight ----------------

__global__ __launch_bounds__(256) void agg16_kernel(
    const _Float16* __restrict__ x, const _Float16* __restrict__ x0,
    const int* __restrict__ row_ptr, const int* __restrict__ col,
    const float* __restrict__ val, const float* __restrict__ dinv,
    short* __restrict__ Hhi, short* __restrict__ Hlo) {
    int node = blockIdx.x * 4 + (threadIdx.x >> 6);
    int lane = threadIdx.x & 63;
    int g = lane >> 4, q = lane & 15;
    const h16x8* x8 = (const h16x8*)x;

    float acc[8];
#pragma unroll
    for (int j = 0; j < 8; ++j) acc[j] = 0.f;

    int p1 = row_ptr[node + 1];
    for (int p = row_ptr[node]; p < p1; p += 16) {
        int4   c4 = *(const int4*)(col + p + 4 * g);
        float4 w4 = *(const float4*)(val + p + 4 * g);
        h16x8 v0 = x8[(size_t)c4.x * 16 + q];
        h16x8 v1 = x8[(size_t)c4.y * 16 + q];
        h16x8 v2 = x8[(size_t)c4.z * 16 + q];
        h16x8 v3 = x8[(size_t)c4.w * 16 + q];
#pragma unroll
        for (int j = 0; j < 8; ++j)
            acc[j] += w4.x * (float)v0[j] + w4.y * (float)v1[j]
                    + w4.z * (float)v2[j] + w4.w * (float)v3[j];
    }

#pragma unroll
    for (int j = 0; j < 8; ++j) {
        acc[j] += __shfl_xor(acc[j], 16, 64);
        acc[j] += __shfl_xor(acc[j], 32, 64);
    }

    if (g == 0) {
        float di = dinv[node], d2 = di * di;
        h16x8 sv = x8[(size_t)node * 16 + q];
        h16x8 zv = ((const h16x8*)x0)[(size_t)node * 16 + q];
        s16x8 hi, lo;
#pragma unroll
        for (int j = 0; j < 8; ++j) {
            float o = 0.9f * (acc[j] + d2 * (float)sv[j]) + 0.1f * (float)zv[j];
            short h, l; split_bf16(o, h, l);
            hi[j] = h; lo[j] = l;
        }
        ((s16x8*)Hhi)[(size_t)node * 16 + q] = hi;
        ((s16x8*)Hlo)[(size_t)node * 16 + q] = lo;
    }
}

// ---------------- final projection ----------------

__global__ __launch_bounds__(256) void final16_kernel(
    const _Float16* __restrict__ x, const float* __restrict__ Wout,
    const float* __restrict__ bout, float* __restrict__ out) {
    int node = blockIdx.x * 4 + (threadIdx.x >> 6);
    int lane = threadIdx.x & 63;
    h16x2 a = ((const h16x2*)x)[(size_t)node * 64 + lane];
    float2 w = ((const float2*)Wout)[lane];
    float v = (float)a[0] * w.x + (float)a[1] * w.y;
#pragma unroll
    for (int off = 32; off; off >>= 1) v += __shfl_down(v, off, 64);
    if (lane == 0) out[node] = v + bout[0];
}

// ---------------- host ----------------

extern "C" void kernel_launch(void* const* d_in, const int* in_sizes, int n_in,
                              void* d_out, int out_size, void* d_ws, size_t ws_size,
                              hipStream_t stream) {
    const float* x_in     = (const float*)d_in[0];
    const int*   ei       = (const int*)d_in[1];
    const float* W_in     = (const float*)d_in[3];
    const float* b_in     = (const float*)d_in[4];
    const float* W_layers = (const float*)d_in[5];
    const float* W_out    = (const float*)d_in[6];
    const float* b_out    = (const float*)d_in[7];
    float* out = (float*)d_out;

    const int* src = ei;
    const int* dst = ei + NE;

    char* ws = (char*)d_ws;
    size_t off = 0;
    auto alloc = [&](size_t bytes) {
        size_t p = off;
        off = (off + bytes + 255) & ~(size_t)255;
        return p;
    };
    int*   deg     = (int*)(ws + alloc((size_t)NN * 4));
    float* dinv    = (float*)(ws + alloc((size_t)NN * 4));
    int*   row_ptr = (int*)(ws + alloc((size_t)(NN + 1) * 4));
    int*   cursor  = (int*)(ws + alloc((size_t)NN * 4));
    int*   bsum    = (int*)(ws + alloc((size_t)NB * 4));
    int*   boff    = (int*)(ws + alloc((size_t)NB * 4));
    int*   col     = (int*)(ws + alloc((size_t)PADMAX * 4));
    float* val     = (float*)(ws + alloc((size_t)PADMAX * 4));
    _Float16* x0h  = (_Float16*)(ws + alloc((size_t)NN * HID * 2));
    _Float16* cur  = (_Float16*)(ws + alloc((size_t)NN * HID * 2));
    short* Hhi     = (short*)(ws + alloc((size_t)NN * HID * 2));
    short* Hlo     = (short*)(ws + alloc((size_t)NN * HID * 2));
    short* Bhi0    = (short*)(ws + alloc((size_t)IN_DIM * HID * 2));
    short* Blo0    = (short*)(ws + alloc((size_t)IN_DIM * HID * 2));
    short* BhiL    = (short*)(ws + alloc((size_t)N_LAYERS * HID * HID * 2));
    short* BloL    = (short*)(ws + alloc((size_t)N_LAYERS * HID * HID * 2));

    hipMemsetAsync(deg, 0, (size_t)NN * 4, stream);
    hipMemsetAsync(col, 0, (size_t)PADMAX * 4, stream);   // pad entries: col 0
    hipMemsetAsync(val, 0, (size_t)PADMAX * 4, stream);   // pad entries: weight 0

    deg_count_kernel<<<NE / 256, 256, 0, stream>>>(dst, deg);
    dinv_kernel<<<(NN + 255) / 256, 256, 0, stream>>>(deg, dinv);
    scan1_kernel<<<NB, 1024, 0, stream>>>(deg, bsum);
    scan2_kernel<<<1, 128, 0, stream>>>(bsum, boff, row_ptr);
    scan3_kernel<<<NB, 1024, 0, stream>>>(deg, boff, row_ptr, cursor);
    fill_kernel<<<NE / 256, 256, 0, stream>>>(src, dst, dinv, cursor, col, val);

    wprep_init_kernel<<<32, 256, 0, stream>>>(W_in, Bhi0, Blo0);
    wprep_layers_kernel<<<64, 256, 0, stream>>>(W_layers, BhiL, BloL);

    int gemm_grid = (NN + 127) / 128;
    init_mfma_kernel<<<gemm_grid, 256, 0, stream>>>(
        x_in, (const s16x8*)Bhi0, (const s16x8*)Blo0, b_in, cur, x0h);

    for (int l = 0; l < N_LAYERS; ++l) {
        agg16_kernel<<<NN / 4, 256, 0, stream>>>(cur, x0h, row_ptr, col, val, dinv, Hhi, Hlo);
        float beta = logf(0.5f / (float)(l + 1) + 1.0f);
        layer_mfma_kernel<<<gemm_grid, 256, 0, stream>>>(
            Hhi, Hlo, (const s16x8*)(BhiL + (size_t)l * HID * HID),
            (const s16x8*)(BloL + (size_t)l * HID * HID), beta, cur);
    }

    final16_kernel<<<NN / 4, 256, 0, stream>>>(cur, W_out, b_out, out);
}

// Round 5
// 1101.360 us; speedup vs baseline: 2.4887x; 1.2115x over previous
//
#include <hip/hip_runtime.h>
#include <math.h>

#define NN 100000
#define NE 1600000
#define IN_DIM 512
#define HID 128
#define N_LAYERS 8
#define NB 98               // ceil(NN/1024)
#define PADMAX 3200000      // NE + 15*NN + slack

typedef __attribute__((ext_vector_type(4))) float f32x4;
typedef __attribute__((ext_vector_type(8))) _Float16 h16x8;
typedef __attribute__((ext_vector_type(2))) _Float16 h16x2;

// ---------------- CSR build (rows padded to multiples of 16) ----------------

__global__ void deg_count_kernel(const int* __restrict__ dst, int* __restrict__ deg) {
    int e = blockIdx.x * blockDim.x + threadIdx.x;
    if (e < NE) atomicAdd(&deg[dst[e]], 1);
}

__global__ void dinv_kernel(const int* __restrict__ deg, float* __restrict__ dinv) {
    int i = blockIdx.x * blockDim.x + threadIdx.x;
    if (i < NN) dinv[i] = rsqrtf((float)(deg[i] + 1));   // +1 self loop
}

__global__ void scan1_kernel(const int* __restrict__ deg, int* __restrict__ bsum) {
    __shared__ int s[16];
    int gi = blockIdx.x * 1024 + threadIdx.x;
    int d = (gi < NN) ? deg[gi] : 0;
    int r = (d + 15) & ~15;                              // padded capacity
    for (int off = 32; off; off >>= 1) r += __shfl_down(r, off, 64);
    if ((threadIdx.x & 63) == 0) s[threadIdx.x >> 6] = r;
    __syncthreads();
    if (threadIdx.x == 0) {
        int t = 0;
        for (int i = 0; i < 16; ++i) t += s[i];
        bsum[blockIdx.x] = t;
    }
}

__global__ void scan2_kernel(const int* __restrict__ bsum, int* __restrict__ boff,
                             int* __restrict__ row_ptr) {
    __shared__ int s[128];
    int tid = threadIdx.x;
    int v = (tid < NB) ? bsum[tid] : 0;
    s[tid] = v;
    __syncthreads();
    for (int off = 1; off < 128; off <<= 1) {
        int t = (tid >= off) ? s[tid - off] : 0;
        __syncthreads();
        s[tid] += t;
        __syncthreads();
    }
    if (tid < NB) boff[tid] = s[tid] - v;   // exclusive
    if (tid == NB - 1) row_ptr[NN] = s[tid];
}

__global__ void scan3_kernel(const int* __restrict__ deg, const int* __restrict__ boff,
                             int* __restrict__ row_ptr, int* __restrict__ cursor) {
    __shared__ int s[1024];
    int tid = threadIdx.x;
    int gi = blockIdx.x * 1024 + tid;
    int d = (gi < NN) ? deg[gi] : 0;
    int v = (d + 15) & ~15;
    s[tid] = v;
    __syncthreads();
    for (int off = 1; off < 1024; off <<= 1) {
        int t = (tid >= off) ? s[tid - off] : 0;
        __syncthreads();
        s[tid] += t;
        __syncthreads();
    }
    if (gi < NN) {
        int o = boff[blockIdx.x] + s[tid] - v;
        row_ptr[gi] = o;
        cursor[gi]  = o;
    }
}

__global__ void pad_kernel(const int* __restrict__ deg, const int* __restrict__ row_ptr,
                           int* __restrict__ col, float* __restrict__ val) {
    int i = blockIdx.x * 256 + threadIdx.x;
    if (i < NN) {
        int d = deg[i];
        int s = row_ptr[i] + d;
        int e = row_ptr[i] + ((d + 15) & ~15);
        for (int p = s; p < e; ++p) { col[p] = 0; val[p] = 0.f; }
    }
}

__global__ void fill_kernel(const int* __restrict__ src, const int* __restrict__ dst,
                            const float* __restrict__ dinv, int* __restrict__ cursor,
                            int* __restrict__ col, float* __restrict__ val) {
    int e = blockIdx.x * blockDim.x + threadIdx.x;
    if (e < NE) {
        int s = src[e], d = dst[e];
        int pos = atomicAdd(&cursor[d], 1);
        col[pos] = s;
        val[pos] = dinv[s] * dinv[d];
    }
}

// ---------------- W prep: fp16 hi/lo split, MFMA B-fragment order ----------------
// B-frag element for (n,kk): B[k = kk*32 + (lane>>4)*8 + j][col = n*16 + (lane&15)]

__global__ void wprep_init_kernel(const float* __restrict__ W,
                                  _Float16* __restrict__ Bhi, _Float16* __restrict__ Blo) {
    int t = blockIdx.x * 256 + threadIdx.x;     // 8 * 16 * 64 = 8192 threads
    if (t >= 8 * 16 * 64) return;
    int lane = t & 63, nkk = t >> 6;
    int n = nkk >> 4, kk = nkk & 15;
    int scol = n * 16 + (lane & 15);
    int sr0 = kk * 32 + (lane >> 4) * 8;
#pragma unroll
    for (int j = 0; j < 8; ++j) {
        float w = W[(size_t)(sr0 + j) * HID + scol];
        _Float16 hi = (_Float16)w;
        _Float16 lo = (_Float16)(w - (float)hi);
        Bhi[(size_t)t * 8 + j] = hi;
        Blo[(size_t)t * 8 + j] = lo;
    }
}

__global__ void wprep_layers_kernel(const float* __restrict__ WL,
                                    _Float16* __restrict__ Bhi, _Float16* __restrict__ Blo) {
    int t = blockIdx.x * 256 + threadIdx.x;     // 8 layers * 8*4*64 = 16384 threads
    if (t >= N_LAYERS * 8 * 4 * 64) return;
    int layer = t >> 11;
    int r = t & 2047;
    int lane = r & 63, nkk = r >> 6;
    int n = nkk >> 2, kk = nkk & 3;
    const float* W = WL + (size_t)layer * HID * HID;
    int scol = n * 16 + (lane & 15);
    int sr0 = kk * 32 + (lane >> 4) * 8;
#pragma unroll
    for (int j = 0; j < 8; ++j) {
        float w = W[(size_t)(sr0 + j) * HID + scol];
        _Float16 hi = (_Float16)w;
        _Float16 lo = (_Float16)(w - (float)hi);
        Bhi[(size_t)t * 8 + j] = hi;
        Blo[(size_t)t * 8 + j] = lo;
    }
}

// ---------------- init projection: fp16(x)[NN][512] @ W[512][128] + b -> fp16 ----------------
// 2 waves/block, 32 rows/wave. Depth-2 register prefetch; A cvt fp32->fp16 in reg.

__global__ __launch_bounds__(128) void init_mfma_kernel(
    const float* __restrict__ x, const h16x8* __restrict__ Bhi, const h16x8* __restrict__ Blo,
    const float* __restrict__ b, _Float16* __restrict__ cur, _Float16* __restrict__ x0h) {
    int lane = threadIdx.x & 63, wid = threadIdx.x >> 6;
    int row0w = blockIdx.x * 64 + wid * 32;
    int rsel = lane & 15, ksel = lane >> 4;

    const float* rp[2];
#pragma unroll
    for (int m = 0; m < 2; ++m) {
        int row = row0w + 16 * m + rsel; if (row >= NN) row = NN - 1;
        rp[m] = x + (size_t)row * IN_DIM + ksel * 8;
    }

    f32x4 acc[2][8];
#pragma unroll
    for (int m = 0; m < 2; ++m)
#pragma unroll
        for (int n = 0; n < 8; ++n) acc[m][n] = (f32x4){0.f, 0.f, 0.f, 0.f};

    float4 pa[2][2], pb[2][2];
#pragma unroll
    for (int s = 0; s < 2; ++s)
#pragma unroll
        for (int m = 0; m < 2; ++m) {
            pa[s][m] = *(const float4*)(rp[m] + s * 32);
            pb[s][m] = *(const float4*)(rp[m] + s * 32 + 4);
        }

#pragma unroll
    for (int kk = 0; kk < 16; ++kk) {
        const int cs = kk & 1;
        h16x8 a[2];
#pragma unroll
        for (int m = 0; m < 2; ++m) {
            float4 va = pa[cs][m], vb = pb[cs][m];
            a[m][0] = (_Float16)va.x; a[m][1] = (_Float16)va.y;
            a[m][2] = (_Float16)va.z; a[m][3] = (_Float16)va.w;
            a[m][4] = (_Float16)vb.x; a[m][5] = (_Float16)vb.y;
            a[m][6] = (_Float16)vb.z; a[m][7] = (_Float16)vb.w;
        }
        if (kk + 2 < 16) {
#pragma unroll
            for (int m = 0; m < 2; ++m) {
                pa[cs][m] = *(const float4*)(rp[m] + (kk + 2) * 32);
                pb[cs][m] = *(const float4*)(rp[m] + (kk + 2) * 32 + 4);
            }
        }
#pragma unroll
        for (int n = 0; n < 8; ++n) {
            h16x8 bh = Bhi[(n * 16 + kk) * 64 + lane];
            h16x8 bl = Blo[(n * 16 + kk) * 64 + lane];
#pragma unroll
            for (int m = 0; m < 2; ++m) {
                acc[m][n] = __builtin_amdgcn_mfma_f32_16x16x32_f16(a[m], bh, acc[m][n], 0, 0, 0);
                acc[m][n] = __builtin_amdgcn_mfma_f32_16x16x32_f16(a[m], bl, acc[m][n], 0, 0, 0);
            }
        }
    }

#pragma unroll
    for (int m = 0; m < 2; ++m)
#pragma unroll
        for (int n = 0; n < 8; ++n) {
            int col = n * 16 + rsel;
            float bias = b[col];
#pragma unroll
            for (int r = 0; r < 4; ++r) {
                int row = row0w + 16 * m + ksel * 4 + r;
                if (row < NN) {
                    float v = acc[m][n][r] + bias;
                    _Float16 hv = (_Float16)v;
                    cur[(size_t)row * HID + col] = hv;
                    x0h[(size_t)row * HID + col] = hv;
                }
            }
        }
}

// ---------------- layer GEMM: cur = relu((1-b)*H + b*(H @ W)) -> fp16 ----------------
// A fragments load directly from fp16 H plane (zero VALU prep); W split fp16 hi+lo.

__global__ __launch_bounds__(128) void layer_mfma_kernel(
    const _Float16* __restrict__ H,
    const h16x8* __restrict__ Bhi, const h16x8* __restrict__ Blo,
    float beta, _Float16* __restrict__ cur) {
    int lane = threadIdx.x & 63, wid = threadIdx.x >> 6;
    int row0w = blockIdx.x * 64 + wid * 32;
    int rsel = lane & 15, ksel = lane >> 4;

    h16x8 a[2][4];
#pragma unroll
    for (int m = 0; m < 2; ++m) {
        int row = row0w + 16 * m + rsel; if (row >= NN) row = NN - 1;
        const _Float16* hp = H + (size_t)row * HID + ksel * 8;
#pragma unroll
        for (int kk = 0; kk < 4; ++kk)
            a[m][kk] = *(const h16x8*)(hp + kk * 32);
    }

    f32x4 acc[2][8];
#pragma unroll
    for (int m = 0; m < 2; ++m)
#pragma unroll
        for (int n = 0; n < 8; ++n) acc[m][n] = (f32x4){0.f, 0.f, 0.f, 0.f};

#pragma unroll
    for (int n = 0; n < 8; ++n)
#pragma unroll
        for (int kk = 0; kk < 4; ++kk) {
            h16x8 bh = Bhi[(n * 4 + kk) * 64 + lane];
            h16x8 bl = Blo[(n * 4 + kk) * 64 + lane];
#pragma unroll
            for (int m = 0; m < 2; ++m) {
                acc[m][n] = __builtin_amdgcn_mfma_f32_16x16x32_f16(a[m][kk], bh, acc[m][n], 0, 0, 0);
                acc[m][n] = __builtin_amdgcn_mfma_f32_16x16x32_f16(a[m][kk], bl, acc[m][n], 0, 0, 0);
            }
        }

    float ob = 1.0f - beta;
#pragma unroll
    for (int m = 0; m < 2; ++m)
#pragma unroll
        for (int n = 0; n < 8; ++n) {
            int col = n * 16 + rsel;
#pragma unroll
            for (int r = 0; r < 4; ++r) {
                int row = row0w + 16 * m + ksel * 4 + r;
                if (row < NN) {
                    size_t o = (size_t)row * HID + col;
                    float h = (float)H[o];
                    float v = ob * h + beta * acc[m][n][r];
                    v = v > 0.f ? v : 0.f;
                    cur[o] = (_Float16)v;
                }
            }
        }
}

// ---------------- sparse aggregation: padded CSR, fp16 gathers, fp16 out ----------------

__global__ __launch_bounds__(256) void agg16_kernel(
    const _Float16* __restrict__ x, const _Float16* __restrict__ x0,
    const int* __restrict__ row_ptr, const int* __restrict__ col,
    const float* __restrict__ val, const float* __restrict__ dinv,
    _Float16* __restrict__ Hout) {
    int node = blockIdx.x * 4 + (threadIdx.x >> 6);
    int lane = threadIdx.x & 63;
    int g = lane >> 4, q = lane & 15;
    const h16x8* x8 = (const h16x8*)x;

    // hoist independent loads ahead of the gather loop
    float di = dinv[node];
    h16x8 sv = x8[(size_t)node * 16 + q];
    h16x8 zv = ((const h16x8*)x0)[(size_t)node * 16 + q];

    float acc[8];
#pragma unroll
    for (int j = 0; j < 8; ++j) acc[j] = 0.f;

    int p1 = row_ptr[node + 1];
#pragma unroll 2
    for (int p = row_ptr[node]; p < p1; p += 16) {
        int4   c4 = *(const int4*)(col + p + 4 * g);
        float4 w4 = *(const float4*)(val + p + 4 * g);
        h16x8 v0 = x8[(size_t)c4.x * 16 + q];
        h16x8 v1 = x8[(size_t)c4.y * 16 + q];
        h16x8 v2 = x8[(size_t)c4.z * 16 + q];
        h16x8 v3 = x8[(size_t)c4.w * 16 + q];
#pragma unroll
        for (int j = 0; j < 8; ++j)
            acc[j] += w4.x * (float)v0[j] + w4.y * (float)v1[j]
                    + w4.z * (float)v2[j] + w4.w * (float)v3[j];
    }

#pragma unroll
    for (int j = 0; j < 8; ++j) {
        acc[j] += __shfl_xor(acc[j], 16, 64);
        acc[j] += __shfl_xor(acc[j], 32, 64);
    }

    if (g == 0) {
        float d2 = di * di;
        h16x8 o16;
#pragma unroll
        for (int j = 0; j < 8; ++j)
            o16[j] = (_Float16)(0.9f * (acc[j] + d2 * (float)sv[j]) + 0.1f * (float)zv[j]);
        ((h16x8*)Hout)[(size_t)node * 16 + q] = o16;
    }
}

// ---------------- final projection ----------------

__global__ __launch_bounds__(256) void final16_kernel(
    const _Float16* __restrict__ x, const float* __restrict__ Wout,
    const float* __restrict__ bout, float* __restrict__ out) {
    int node = blockIdx.x * 4 + (threadIdx.x >> 6);
    int lane = threadIdx.x & 63;
    h16x2 a = ((const h16x2*)x)[(size_t)node * 64 + lane];
    float2 w = ((const float2*)Wout)[lane];
    float v = (float)a[0] * w.x + (float)a[1] * w.y;
#pragma unroll
    for (int off = 32; off; off >>= 1) v += __shfl_down(v, off, 64);
    if (lane == 0) out[node] = v + bout[0];
}

// ---------------- host ----------------

extern "C" void kernel_launch(void* const* d_in, const int* in_sizes, int n_in,
                              void* d_out, int out_size, void* d_ws, size_t ws_size,
                              hipStream_t stream) {
    const float* x_in     = (const float*)d_in[0];
    const int*   ei       = (const int*)d_in[1];
    const float* W_in     = (const float*)d_in[3];
    const float* b_in     = (const float*)d_in[4];
    const float* W_layers = (const float*)d_in[5];
    const float* W_out    = (const float*)d_in[6];
    const float* b_out    = (const float*)d_in[7];
    float* out = (float*)d_out;

    const int* src = ei;
    const int* dst = ei + NE;

    char* ws = (char*)d_ws;
    size_t off = 0;
    auto alloc = [&](size_t bytes) {
        size_t p = off;
        off = (off + bytes + 255) & ~(size_t)255;
        return p;
    };
    int*   deg     = (int*)(ws + alloc((size_t)NN * 4));
    float* dinv    = (float*)(ws + alloc((size_t)NN * 4));
    int*   row_ptr = (int*)(ws + alloc((size_t)(NN + 1) * 4));
    int*   cursor  = (int*)(ws + alloc((size_t)NN * 4));
    int*   bsum    = (int*)(ws + alloc((size_t)NB * 4));
    int*   boff    = (int*)(ws + alloc((size_t)NB * 4));
    int*   col     = (int*)(ws + alloc((size_t)PADMAX * 4));
    float* val     = (float*)(ws + alloc((size_t)PADMAX * 4));
    _Float16* x0h  = (_Float16*)(ws + alloc((size_t)NN * HID * 2));
    _Float16* cur  = (_Float16*)(ws + alloc((size_t)NN * HID * 2));
    _Float16* Hbuf = (_Float16*)(ws + alloc((size_t)NN * HID * 2));
    _Float16* Bhi0 = (_Float16*)(ws + alloc((size_t)IN_DIM * HID * 2));
    _Float16* Blo0 = (_Float16*)(ws + alloc((size_t)IN_DIM * HID * 2));
    _Float16* BhiL = (_Float16*)(ws + alloc((size_t)N_LAYERS * HID * HID * 2));
    _Float16* BloL = (_Float16*)(ws + alloc((size_t)N_LAYERS * HID * HID * 2));

    hipMemsetAsync(deg, 0, (size_t)NN * 4, stream);

    deg_count_kernel<<<NE / 256, 256, 0, stream>>>(dst, deg);
    dinv_kernel<<<(NN + 255) / 256, 256, 0, stream>>>(deg, dinv);
    scan1_kernel<<<NB, 1024, 0, stream>>>(deg, bsum);
    scan2_kernel<<<1, 128, 0, stream>>>(bsum, boff, row_ptr);
    scan3_kernel<<<NB, 1024, 0, stream>>>(deg, boff, row_ptr, cursor);
    pad_kernel<<<(NN + 255) / 256, 256, 0, stream>>>(deg, row_ptr, col, val);
    fill_kernel<<<NE / 256, 256, 0, stream>>>(src, dst, dinv, cursor, col, val);

    wprep_init_kernel<<<32, 256, 0, stream>>>(W_in, Bhi0, Blo0);
    wprep_layers_kernel<<<64, 256, 0, stream>>>(W_layers, BhiL, BloL);

    int gemm_grid = (NN + 63) / 64;
    init_mfma_kernel<<<gemm_grid, 128, 0, stream>>>(
        x_in, (const h16x8*)Bhi0, (const h16x8*)Blo0, b_in, cur, x0h);

    for (int l = 0; l < N_LAYERS; ++l) {
        agg16_kernel<<<NN / 4, 256, 0, stream>>>(cur, x0h, row_ptr, col, val, dinv, Hbuf);
        float beta = logf(0.5f / (float)(l + 1) + 1.0f);
        layer_mfma_kernel<<<gemm_grid, 128, 0, stream>>>(
            Hbuf, (const h16x8*)(BhiL + (size_t)l * HID * HID),
            (const h16x8*)(BloL + (size_t)l * HID * HID), beta, cur);
    }

    final16_kernel<<<NN / 4, 256, 0, stream>>>(cur, W_out, b_out, out);
}